// Round 7
// baseline (918.042 us; speedup 1.0000x reference)
//
#include <hip/hip_runtime.h>
#include <hip/hip_bf16.h>
#include <stdint.h>

// Problem constants (FujiSparseMoE): S=2048 B=2 D=1024 E=64 K=2 I=512 SI=512 CAP=256
#define T_TOK 4096
#define DDIM  1024
#define NEXP  64
#define IDIM  512
#define SIDIM 512
#define CAP   256
#define KZ    8     // logits K-split

typedef __attribute__((ext_vector_type(4))) float f32x4;
typedef __attribute__((ext_vector_type(8))) short bf16x8;   // 8 bf16 raw (4 VGPRs)

// 8 fp32 -> 8 bf16 (RNE) via packed converts
__device__ __forceinline__ bf16x8 cvt8(f32x4 a, f32x4 b) {
    union { __hip_bfloat162 h[4]; bf16x8 v; } u;
    u.h[0] = __float22bfloat162_rn(make_float2(a[0], a[1]));
    u.h[1] = __float22bfloat162_rn(make_float2(a[2], a[3]));
    u.h[2] = __float22bfloat162_rn(make_float2(b[0], b[1]));
    u.h[3] = __float22bfloat162_rn(make_float2(b[2], b[3]));
    return u.v;
}
__device__ __forceinline__ short f2bs(float f) {
    union { __hip_bfloat16 h; short s; } u; u.h = __float2bfloat16(f); return u.s;
}

// ---------------- logits partials (fp32 exact): lpart[kz][T,E]
__global__ __launch_bounds__(256) void logits_kernel(const float* __restrict__ X,
                                                     const float* __restrict__ RW,
                                                     float* __restrict__ lpart) {
    __shared__ float sX[64 * 33];
    __shared__ float sW[64 * 33];
    int m0 = blockIdx.x * 64;
    int kz = blockIdx.y;               // 0..7
    int kbase = kz * (DDIM / KZ);      // 128 K each
    int tid = threadIdx.x;
    int tg = tid >> 4;
    int eg = tid & 15;
    float acc[4][4] = {};
    for (int k0 = 0; k0 < DDIM / KZ; k0 += 32) {
        __syncthreads();
#pragma unroll
        for (int i = 0; i < 8; ++i) {
            int idx = i * 256 + tid;
            int r = idx >> 5, c = idx & 31;
            sX[r * 33 + c] = X[(size_t)(m0 + r) * DDIM + kbase + k0 + c];
            sW[r * 33 + c] = RW[(size_t)r * DDIM + kbase + k0 + c];
        }
        __syncthreads();
#pragma unroll 4
        for (int k = 0; k < 32; ++k) {
            float xv[4], wv[4];
#pragma unroll
            for (int i = 0; i < 4; ++i) xv[i] = sX[(tg * 4 + i) * 33 + k];
#pragma unroll
            for (int j = 0; j < 4; ++j) wv[j] = sW[(eg * 4 + j) * 33 + k];
#pragma unroll
            for (int i = 0; i < 4; ++i)
#pragma unroll
                for (int j = 0; j < 4; ++j) acc[i][j] += xv[i] * wv[j];
        }
    }
    float* outp = lpart + (size_t)kz * T_TOK * NEXP;
#pragma unroll
    for (int i = 0; i < 4; ++i)
#pragma unroll
        for (int j = 0; j < 4; ++j)
            outp[(size_t)(m0 + tg * 4 + i) * NEXP + eg * 4 + j] = acc[i][j];
}

// ---------------- softmax + top2 + dispatch + probs out + shared sigmoid gate
__global__ __launch_bounds__(256) void topk_kernel(const float* __restrict__ lpart,
                                                   const float* __restrict__ X,
                                                   const float* __restrict__ SEG,
                                                   float* __restrict__ probs_out,
                                                   int* __restrict__ counts,
                                                   int* __restrict__ tok_slot,
                                                   float* __restrict__ w_slot,
                                                   float* __restrict__ gate_sh) {
    int lane = threadIdx.x & 63;
    int wv   = threadIdx.x >> 6;
    int t    = blockIdx.x * 4 + wv;
    size_t li = (size_t)t * NEXP + lane;
    float l = 0.f;
#pragma unroll
    for (int z = 0; z < KZ; ++z) l += lpart[(size_t)z * T_TOK * NEXP + li];
    float mx = l;
    for (int s = 32; s; s >>= 1) mx = fmaxf(mx, __shfl_xor(mx, s));
    float e = __expf(l - mx);
    float sum = e;
    for (int s = 32; s; s >>= 1) sum += __shfl_xor(sum, s);
    float prob = e / sum;
    probs_out[li] = prob;
    float v = prob; int idx = lane;
    for (int s = 32; s; s >>= 1) {
        float ov = __shfl_xor(v, s); int oi = __shfl_xor(idx, s);
        if (ov > v || (ov == v && oi < idx)) { v = ov; idx = oi; }
    }
    float v1 = v; int i1 = idx;
    v = (lane == i1) ? -1e30f : prob; idx = lane;
    for (int s = 32; s; s >>= 1) {
        float ov = __shfl_xor(v, s); int oi = __shfl_xor(idx, s);
        if (ov > v || (ov == v && oi < idx)) { v = ov; idx = oi; }
    }
    float v2 = v; int i2 = idx;
    float denom = v1 + v2 + 1e-9f;
    if (lane == 0) {
        int s1 = atomicAdd(&counts[i1], 1);
        if (s1 < CAP) { tok_slot[i1 * CAP + s1] = t; w_slot[i1 * CAP + s1] = v1 / denom; }
        int s2 = atomicAdd(&counts[i2], 1);
        if (s2 < CAP) { tok_slot[i2 * CAP + s2] = t; w_slot[i2 * CAP + s2] = v2 / denom; }
    }
    float g = 0.f;
    const float* xr = X + (size_t)t * DDIM + lane * 16;
    const float* sr = SEG + lane * 16;
#pragma unroll
    for (int j = 0; j < 4; ++j) {
        f32x4 xv = *(const f32x4*)(xr + j * 4);
        f32x4 sv = *(const f32x4*)(sr + j * 4);
#pragma unroll
        for (int q = 0; q < 4; ++q) g += xv[q] * sv[q];
    }
    for (int s = 32; s; s >>= 1) g += __shfl_xor(g, s);
    if (lane == 0) gate_sh[t] = 1.f / (1.f + __expf(-g));
}

// ---------------- gather X -> xg (bf16, per expert slot) and X -> xsh (bf16)
__global__ __launch_bounds__(256) void xgather(const float* __restrict__ X,
                                               const int* __restrict__ counts,
                                               const int* __restrict__ tok_slot,
                                               short* __restrict__ xg,
                                               short* __restrict__ xsh) {
    int b = blockIdx.x, tid = threadIdx.x;
    if (b < 512) {
        int r = b & 7, j = b >> 3;
        int e = (j & 7) * 8 + r;                // e%8 == b%8 -> writer XCD matches GEMM reader
        int s0 = (j >> 3) * 32;
        int M = counts[e]; if (M > CAP) M = CAP;
        for (int i = tid; i < 32 * 128; i += 256) {
            int sl = s0 + (i >> 7);
            int ch = i & 127;
            int src = (sl < M) ? tok_slot[e * CAP + sl] : 0;
            const float* p = X + (size_t)src * DDIM + ch * 8;
            f32x4 lo = *(const f32x4*)p, hi = *(const f32x4*)(p + 4);
            *(bf16x8*)(xg + ((size_t)e * CAP + sl) * DDIM + ch * 8) = cvt8(lo, hi);
        }
    } else {
        int r0 = (b - 512) * 32;
        for (int i = tid; i < 32 * 128; i += 256) {
            int row = r0 + (i >> 7), ch = i & 127;
            const float* p = X + (size_t)row * DDIM + ch * 8;
            f32x4 lo = *(const f32x4*)p, hi = *(const f32x4*)(p + 4);
            *(bf16x8*)(xsh + (size_t)row * DDIM + ch * 8) = cvt8(lo, hi);
        }
    }
}

// ---------------- gate/up GEMM + SwiGLU -> act: ZERO LDS, ZERO BARRIERS.
// Each wave computes its 64x32 tile independently: A (bf16) and B (fp32 weights)
// loaded straight to VGPRs with a manual 2-deep register pipeline; B cvt'd at use.
// No __syncthreads in the K-loop -> no barrier-coupled tail-latency amplification;
// waves dephase freely. Block = 4 waves (2m x 2n), tile 128x64(g)+64(u).
// Grid 1280: f<1024 expert (e%8==f%8 XCD-pinned, 2 mb x 8 nb), f>=1024 shared (32 mb x 8 nb).
__global__ __launch_bounds__(256, 2) void gateup_all(const short* __restrict__ xg,
                                                     const short* __restrict__ xsh,
                                                     const float* __restrict__ GUP,
                                                     const float* __restrict__ SG,
                                                     const float* __restrict__ SU,
                                                     const int* __restrict__ counts,
                                                     short* __restrict__ act,
                                                     short* __restrict__ act_sh) {
    int f = blockIdx.x;
    bool expert = f < 1024;
    int e = 0, m0, n0, M;
    const float *Wg, *Wu;
    const short* Abase;
    short* act_out;
    size_t out_base, arow0;
    if (expert) {
        int r = f & 7, q = (f >> 3) & 7;
        e = q * 8 + r;
        n0 = ((f >> 6) & 7) * 64;
        m0 = ((f >> 9) & 1) * 128;
        M = counts[e]; if (M > CAP) M = CAP;
        if (m0 >= M) return;
        Wg = GUP + (size_t)e * (2 * IDIM) * DDIM;
        Wu = Wg + (size_t)IDIM * DDIM;
        Abase = xg; arow0 = (size_t)e * CAP + m0;
        act_out = act; out_base = (size_t)e * CAP * IDIM;
    } else {
        int g = f - 1024;
        m0 = (g & 31) * 128; n0 = ((g >> 5) & 7) * 64;
        M = T_TOK; Wg = SG; Wu = SU;
        Abase = xsh; arow0 = (size_t)m0;
        act_out = act_sh; out_base = 0;
    }
    int tid = threadIdx.x, lane = tid & 63, wv = tid >> 6;
    int wm = wv >> 1, wn = wv & 1;
    int fm = lane & 15, sk = lane >> 4;

    // per-lane operand row pointers (k advances by element offset)
    const short* apA[4];
#pragma unroll
    for (int mt = 0; mt < 4; ++mt)
        apA[mt] = Abase + (arow0 + wm * 64 + mt * 16 + fm) * DDIM + sk * 8;
    const float *bpg[2], *bpu[2];
#pragma unroll
    for (int nt = 0; nt < 2; ++nt) {
        int row = n0 + wn * 32 + nt * 16 + fm;
        bpg[nt] = Wg + (size_t)row * DDIM + sk * 8;
        bpu[nt] = Wu + (size_t)row * DDIM + sk * 8;
    }

    struct R { bf16x8 a[4]; f32x4 g[4]; f32x4 u[4]; };
    R r0, r1;
    auto load = [&](R& r, int k) {
#pragma unroll
        for (int mt = 0; mt < 4; ++mt) r.a[mt] = *(const bf16x8*)(apA[mt] + k);
#pragma unroll
        for (int nt = 0; nt < 2; ++nt) {
            r.g[2 * nt]     = *(const f32x4*)(bpg[nt] + k);
            r.g[2 * nt + 1] = *(const f32x4*)(bpg[nt] + k + 4);
            r.u[2 * nt]     = *(const f32x4*)(bpu[nt] + k);
            r.u[2 * nt + 1] = *(const f32x4*)(bpu[nt] + k + 4);
        }
    };
    f32x4 accg[4][2] = {}, accu[4][2] = {};
    auto compute = [&](const R& r) {
        bf16x8 bg[2], bu[2];
#pragma unroll
        for (int nt = 0; nt < 2; ++nt) {
            bg[nt] = cvt8(r.g[2 * nt], r.g[2 * nt + 1]);
            bu[nt] = cvt8(r.u[2 * nt], r.u[2 * nt + 1]);
        }
#pragma unroll
        for (int mt = 0; mt < 4; ++mt) {
#pragma unroll
            for (int nt = 0; nt < 2; ++nt) {
                accg[mt][nt] = __builtin_amdgcn_mfma_f32_16x16x32_bf16(r.a[mt], bg[nt], accg[mt][nt], 0, 0, 0);
                accu[mt][nt] = __builtin_amdgcn_mfma_f32_16x16x32_bf16(r.a[mt], bu[nt], accu[mt][nt], 0, 0, 0);
            }
        }
    };

    load(r0, 0);
#pragma unroll 1
    for (int k = 0; k < DDIM; k += 64) {
        load(r1, k + 32);
        compute(r0);
        load(r0, (k + 64 < DDIM) ? (k + 64) : 0);   // wrap read: valid memory, result unused
        compute(r1);
    }

    int frow = (lane >> 4) * 4, fcol = lane & 15;
#pragma unroll
    for (int mt = 0; mt < 4; ++mt)
#pragma unroll
        for (int r = 0; r < 4; ++r) {
            int row = m0 + wm * 64 + mt * 16 + frow + r;
            if (row < M) {
#pragma unroll
                for (int nt = 0; nt < 2; ++nt) {
                    float g = accg[mt][nt][r];
                    float u = accu[mt][nt][r];
                    float a = (g / (1.f + __expf(-g))) * u;      // silu(g)*u
                    act_out[out_base + (size_t)row * IDIM + (n0 + wn * 32 + nt * 16 + fcol)] = f2bs(a);
                }
            }
        }
}

// ---------------- down GEMM: ZERO LDS, ZERO BARRIERS, atomicAdd into zeroed out.
// Wave tile 64x64, block 2x2 waves = 128x128. A bf16 (act), B fp32 (DW/SD) reg-pipelined.
// Grid 1280: f<1024 expert (2 mb x 8 nb), f>=1024 shared (32 mb x 8 nb).
__global__ __launch_bounds__(256, 2) void down_all(const short* __restrict__ act,
                                                   const short* __restrict__ act_sh,
                                                   const float* __restrict__ DW,
                                                   const float* __restrict__ SD,
                                                   const int* __restrict__ counts,
                                                   const int* __restrict__ tok_slot,
                                                   const float* __restrict__ w_slot,
                                                   const float* __restrict__ gate_sh,
                                                   float* __restrict__ out) {
    const int KD = IDIM;               // 512 both paths
    int f = blockIdx.x;
    bool expert = f < 1024;
    int e = 0, m0, n0, M;
    const short* A;
    const float* W;
    if (expert) {
        int r = f & 7, q = (f >> 3) & 7;
        e = q * 8 + r;
        n0 = ((f >> 6) & 7) * 128;
        m0 = ((f >> 9) & 1) * 128;
        M = counts[e]; if (M > CAP) M = CAP;
        if (m0 >= M) return;
        A = act + (size_t)e * CAP * IDIM;
        W = DW + (size_t)e * DDIM * IDIM;
    } else {
        int g = f - 1024;
        m0 = (g & 31) * 128; n0 = ((g >> 5) & 7) * 128;
        M = T_TOK; A = act_sh; W = SD;
    }
    int tid = threadIdx.x, lane = tid & 63, wv = tid >> 6;
    int wm = wv >> 1, wn = wv & 1;
    int fm = lane & 15, sk = lane >> 4;

    const short* apA[4];
#pragma unroll
    for (int mt = 0; mt < 4; ++mt)
        apA[mt] = A + (size_t)(m0 + wm * 64 + mt * 16 + fm) * KD + sk * 8;
    const float* bp[4];
#pragma unroll
    for (int nt = 0; nt < 4; ++nt)
        bp[nt] = W + (size_t)(n0 + wn * 64 + nt * 16 + fm) * KD + sk * 8;

    struct R { bf16x8 a[4]; f32x4 b[8]; };
    R r0, r1;
    auto load = [&](R& r, int k) {
#pragma unroll
        for (int mt = 0; mt < 4; ++mt) r.a[mt] = *(const bf16x8*)(apA[mt] + k);
#pragma unroll
        for (int nt = 0; nt < 4; ++nt) {
            r.b[2 * nt]     = *(const f32x4*)(bp[nt] + k);
            r.b[2 * nt + 1] = *(const f32x4*)(bp[nt] + k + 4);
        }
    };
    f32x4 acc[4][4] = {};
    auto compute = [&](const R& r) {
        bf16x8 b[4];
#pragma unroll
        for (int nt = 0; nt < 4; ++nt) b[nt] = cvt8(r.b[2 * nt], r.b[2 * nt + 1]);
#pragma unroll
        for (int mt = 0; mt < 4; ++mt)
#pragma unroll
            for (int nt = 0; nt < 4; ++nt)
                acc[mt][nt] = __builtin_amdgcn_mfma_f32_16x16x32_bf16(r.a[mt], b[nt], acc[mt][nt], 0, 0, 0);
    };

    load(r0, 0);
#pragma unroll 1
    for (int k = 0; k < KD; k += 64) {
        load(r1, k + 32);
        compute(r0);
        load(r0, (k + 64 < KD) ? (k + 64) : 0);
        compute(r1);
    }

    int frow = (lane >> 4) * 4, fcol = lane & 15;
#pragma unroll
    for (int mt = 0; mt < 4; ++mt)
#pragma unroll
        for (int r = 0; r < 4; ++r) {
            int row = m0 + wm * 64 + mt * 16 + frow + r;
            if (row >= M) continue;
            float scale; int trow;
            if (expert) { scale = w_slot[e * CAP + row]; trow = tok_slot[e * CAP + row]; }
            else        { scale = gate_sh[row];          trow = row; }
#pragma unroll
            for (int nt = 0; nt < 4; ++nt) {
                int col = n0 + wn * 64 + nt * 16 + fcol;
                atomicAdd(&out[(size_t)trow * DDIM + col], acc[mt][nt][r] * scale);
            }
        }
}

extern "C" void kernel_launch(void* const* d_in, const int* in_sizes, int n_in,
                              void* d_out, int out_size, void* d_ws, size_t ws_size,
                              hipStream_t stream) {
    const float* X   = (const float*)d_in[0];   // hidden_states  [T, D] fp32
    const float* RW  = (const float*)d_in[1];   // router_w       [E, D]
    const float* GUP = (const float*)d_in[2];   // gate_up_proj   [E, 2I, D]
    const float* DW  = (const float*)d_in[3];   // down_proj      [E, D, I]
    const float* SG  = (const float*)d_in[4];   // sh_gate_w      [SI, D]
    const float* SU  = (const float*)d_in[5];   // sh_up_w        [SI, D]
    const float* SD  = (const float*)d_in[6];   // sh_down_w      [D, SI]
    const float* SEG = (const float*)d_in[7];   // sh_expert_gate_w [1, D]
    float* out = (float*)d_out;                 // [T*D] out, then [T*E] probs (fp32)

    char* ws = (char*)d_ws;
    size_t off = 0;
    float* lpart    = (float*)(ws + off); off += (size_t)KZ * T_TOK * NEXP * 4;  // 8 MB
    int*   counts   = (int*)  (ws + off); off += 1024;
    int*   tok_slot = (int*)  (ws + off); off += (size_t)NEXP * CAP * 4;        // 64 KB
    float* w_slot   = (float*)(ws + off); off += (size_t)NEXP * CAP * 4;        // 64 KB
    float* gate_sh  = (float*)(ws + off); off += (size_t)T_TOK * 4;             // 16 KB
    short* act      = (short*)(ws + off); off += (size_t)NEXP * CAP * IDIM * 2; // 16 MB
    short* act_sh   = (short*)(ws + off); off += (size_t)T_TOK * SIDIM * 2;     // 4 MB
    short* xg       = (short*)(ws + off); off += (size_t)NEXP * CAP * DDIM * 2; // 32 MB
    short* xsh      = (short*)(ws + off); off += (size_t)T_TOK * DDIM * 2;      // 8 MB
    (void)ws_size; (void)in_sizes; (void)n_in; (void)out_size;

    hipMemsetAsync(counts, 0, NEXP * sizeof(int), stream);
    hipMemsetAsync(out, 0, (size_t)T_TOK * DDIM * sizeof(float), stream);  // down_all atomicAdds

    logits_kernel<<<dim3(T_TOK / 64, KZ), 256, 0, stream>>>(X, RW, lpart);
    topk_kernel<<<T_TOK / 4, 256, 0, stream>>>(lpart, X, SEG,
                                               out + (size_t)T_TOK * DDIM,
                                               counts, tok_slot, w_slot, gate_sh);
    xgather<<<640, 256, 0, stream>>>(X, counts, tok_slot, xg, xsh);
    gateup_all<<<1280, 256, 0, stream>>>(xg, xsh, GUP, SG, SU, counts, act, act_sh);
    down_all<<<1280, 256, 0, stream>>>(act, act_sh, DW, SD, counts, tok_slot,
                                       w_slot, gate_sh, out);
}